// Round 8
// baseline (290.500 us; speedup 1.0000x reference)
//
#include <hip/hip_runtime.h>
#include <hip/hip_bf16.h>
#include <math.h>

// Sizes (fixed by the problem)
#define BATCH 16
#define TLEN  512
#define HD    16     // per-direction hidden
#define HID   32     // 2*HD

typedef float v2f __attribute__((ext_vector_type(2)));

// Static device scratch — avoids any assumption about ws_size.
// All arrays fully written before read each call; g_cnt/g_accum are zero-init
// .bss and restored to 0 by the last-arriver block each call.
__device__ float g_outBT[BATCH * TLEN * HID];   // 1 MB
__device__ float g_preA [BATCH * TLEN * HID];   // 1 MB
__device__ float g_Ct   [BATCH * HID * TLEN];   // 1 MB
__device__ float g_un   [BATCH * TLEN];
__device__ float g_w2d  [BATCH * TLEN];
__device__ float g_accum[BATCH];                // zero-initialized, self-resetting
__device__ int   g_cnt  [BATCH];                // zero-initialized, self-resetting

__device__ __forceinline__ float sigm_(float x) {
    return 1.0f / (1.0f + __expf(-x));
}
__device__ __forceinline__ float tanh_(float x) {
    float e = __expf(2.0f * x);
    return 1.0f - 2.0f / (e + 1.0f);
}

__device__ __forceinline__ v2f pk_fma(v2f a, v2f b, v2f c) {
#if __has_builtin(__builtin_elementwise_fma)
    return __builtin_elementwise_fma(a, b, c);   // -> v_pk_fma_f32
#else
    v2f r; r.x = fmaf(a.x, b.x, c.x); r.y = fmaf(a.y, b.y, c.y); return r;
#endif
}

// ---------------------------------------------------------------------------
// K1: bidirectional LSTM. 8 blocks x 64 threads; each wave carries 4 chains.
// Lane = (q = batch slot, u = unit). Recurrent h-distribution fused into the
// gate dots via a DPP row_ror:1 rotation chain (verified: absmax 0.0).
// Weights: 32 INDIVIDUALLY-NAMED v2f scalars (no array -> no alloca -> no
// scratch; round 7 showed VGPR=52 with arrays: weights lived in scratch and
// were re-read every step). Volatile loads keep them once-only.
// ---------------------------------------------------------------------------
__global__ __launch_bounds__(64, 1) void k1_lstm(
    const float* __restrict__ sent,   // [B,T]
    const float* __restrict__ h0,     // [2,B,16]
    const float* __restrict__ c0,     // [2,B,16]
    const float* __restrict__ Wih_f, const float* __restrict__ Whh_f, const float* __restrict__ b_f,
    const float* __restrict__ Wih_b, const float* __restrict__ Whh_b, const float* __restrict__ b_b)
{
    const int blk  = blockIdx.x;      // 0..7
    const int dir  = blk >> 2;        // 0 fwd, 1 bwd
    const int bg   = blk & 3;         // batch group of 4
    const int lane = threadIdx.x;
    const int q    = lane >> 4;       // batch slot in wave
    const int u    = lane & 15;       // hidden unit
    const int b    = bg * 4 + q;

    volatile const float* Wih  = dir ? Wih_b : Wih_f;
    volatile const float* Whh  = dir ? Whh_b : Whh_f;
    volatile const float* bias = dir ? b_b   : b_f;

    // Pre-rotated gate rows for unit u (torch order i,f,g,o at u,+16,+32,+48):
    // w*K multiplies h[(u-K)&15] (the value arriving after K row_ror:1 steps).
    v2f wIF0, wIF1, wIF2,  wIF3,  wIF4,  wIF5,  wIF6,  wIF7,
        wIF8, wIF9, wIF10, wIF11, wIF12, wIF13, wIF14, wIF15;
    v2f wGO0, wGO1, wGO2,  wGO3,  wGO4,  wGO5,  wGO6,  wGO7,
        wGO8, wGO9, wGO10, wGO11, wGO12, wGO13, wGO14, wGO15;

#define LDW(K)                                                     \
    do {                                                           \
        const int m = (u - K) & 15;                                \
        wIF##K.x = Whh[(u)      * 16 + m];                         \
        wIF##K.y = Whh[(u + 16) * 16 + m];                         \
        wGO##K.x = Whh[(u + 32) * 16 + m];                         \
        wGO##K.y = Whh[(u + 48) * 16 + m];                         \
    } while (0)

    LDW(0);  LDW(1);  LDW(2);  LDW(3);  LDW(4);  LDW(5);  LDW(6);  LDW(7);
    LDW(8);  LDW(9);  LDW(10); LDW(11); LDW(12); LDW(13); LDW(14); LDW(15);
#undef LDW

    const float wxI = Wih[u], wxF = Wih[u + 16], wxG = Wih[u + 32], wxO = Wih[u + 48];
    const float bI = bias[u], bF = bias[u + 16], bG = bias[u + 32], bO = bias[u + 48];

    // per-lane state: this lane's own h (unit u) and c
    float hn = h0[dir * (BATCH * HD) + b * HD + u];
    float c  = c0[dir * (BATCH * HD) + b * HD + u];

    const float* srow = sent + b * TLEN;
    float* obase = g_outBT + (size_t)b * TLEN * HID + dir * HD + u;

    // double-buffered x chunk (4 steps per chunk); bwd consumes reversed
    float4 xc = *(const float4*)(srow + (dir ? (TLEN - 4) : 0));
    for (int tb = 0; tb < TLEN; tb += 4) {
        float4 xn = xc;
        if (tb + 4 < TLEN)
            xn = *(const float4*)(srow + (dir ? (TLEN - 8 - tb) : (tb + 4)));
        float xa[4];
        if (dir) { xa[0] = xc.w; xa[1] = xc.z; xa[2] = xc.y; xa[3] = xc.x; }
        else     { xa[0] = xc.x; xa[1] = xc.y; xa[2] = xc.z; xa[3] = xc.w; }

        #pragma unroll
        for (int s2 = 0; s2 < 4; ++s2) {
            const int t   = tb + s2;
            const int pos = dir ? (TLEN - 1 - t) : t;
            const float x = xa[s2];

            v2f pIF, pGO;
            pIF.x = fmaf(x, wxI, bI);
            pIF.y = fmaf(x, wxF, bF);
            pGO.x = fmaf(x, wxG, bG);
            pGO.y = fmaf(x, wxO, bO);

            // rotate-fused dot: cur visits h[(u-k)&15] for k=0..15
            int cur = __float_as_int(hn);
#define GSTEP(K)                                                           \
    do {                                                                   \
        const float hv = __int_as_float(cur);                              \
        v2f hvv; hvv.x = hv; hvv.y = hv;                                   \
        pIF = pk_fma(wIF##K, hvv, pIF);                                    \
        pGO = pk_fma(wGO##K, hvv, pGO);                                    \
        if (K < 15)                                                        \
            cur = __builtin_amdgcn_mov_dpp(cur, 0x121, 0xF, 0xF, true);    \
    } while (0)
            GSTEP(0);  GSTEP(1);  GSTEP(2);  GSTEP(3);
            GSTEP(4);  GSTEP(5);  GSTEP(6);  GSTEP(7);
            GSTEP(8);  GSTEP(9);  GSTEP(10); GSTEP(11);
            GSTEP(12); GSTEP(13); GSTEP(14); GSTEP(15);
#undef GSTEP

            const float ai = sigm_(pIF.x), af = sigm_(pIF.y), ao = sigm_(pGO.y);
            const float ag = tanh_(pGO.x);
            c = fmaf(af, c, ai * ag);
            hn = ao * tanh_(c);

            obase[(size_t)pos * HID] = hn;
        }
        xc = xn;
    }
}

// ---------------------------------------------------------------------------
// K2: projections. Thread per (b,t). W1 etc. staged in LDS.
//   preA[b][t][h] = out[b,t,:] . W1[h,0:32]  + b1[h]
//   Ct  [b][h][t] = out[b,t,:] . W1[h,32:64]           (transposed for K34)
//   un  [b][t]    = out . Wu + bu
//   w2d [b][t]    = out . Wout
// ---------------------------------------------------------------------------
__global__ __launch_bounds__(256) void k2_proj(
    const float* __restrict__ W1,     // [32,64]
    const float* __restrict__ b1,     // [32]
    const float* __restrict__ Wu,     // [32]
    const float* __restrict__ bu,     // [1]
    const float* __restrict__ Wout)   // [32]
{
    __shared__ float w1s[HID * 64];
    __shared__ float b1s[HID], wus[HID], wos[HID];
    const int tid = threadIdx.x;
    for (int k = tid; k < HID * 64; k += 256) w1s[k] = W1[k];
    if (tid < HID) { b1s[tid] = b1[tid]; wus[tid] = Wu[tid]; wos[tid] = Wout[tid]; }
    __syncthreads();

    const int g = blockIdx.x * 256 + tid;    // 0..8191
    const int b = g >> 9;
    const int t = g & (TLEN - 1);

    float o[32];
    const float4* src = (const float4*)(g_outBT + (size_t)g * HID);
    #pragma unroll
    for (int qq = 0; qq < 8; ++qq) {
        float4 v = src[qq];
        o[qq * 4 + 0] = v.x; o[qq * 4 + 1] = v.y; o[qq * 4 + 2] = v.z; o[qq * 4 + 3] = v.w;
    }

    float* pa = g_preA + (size_t)g * HID;
    float* ct = g_Ct + (size_t)b * HID * TLEN + t;
    #pragma unroll 4
    for (int h = 0; h < HID; ++h) {
        float a = b1s[h], cacc = 0.f;
        const float* wr = &w1s[h * 64];
        #pragma unroll
        for (int k = 0; k < HID; ++k) {
            a    = fmaf(o[k], wr[k], a);
            cacc = fmaf(o[k], wr[32 + k], cacc);
        }
        pa[h] = a;
        ct[(size_t)h * TLEN] = cacc;
    }

    float ua = 0.f, wa = 0.f;
    #pragma unroll
    for (int k = 0; k < HID; ++k) { ua = fmaf(o[k], wus[k], ua); wa = fmaf(o[k], wos[k], wa); }
    g_un[g]  = ua + bu[0];
    g_w2d[g] = wa;
}

// ---------------------------------------------------------------------------
// K34: S[b,i] = sum_j sum_h relu(preA[b,i,h] + Ct[b,h,j]) * W2[h]
//      prob[b,i] = sigmoid((S - diag_i + 511*b2)/100 + un[b,i])
//      out[b] = sum_i prob[b,i]*w2d[b,i] / 512 + bout   (fused, O(1)-atomic tail)
// ---------------------------------------------------------------------------
__global__ __launch_bounds__(256) void k34_binary(
    const float* __restrict__ W2,     // [32]
    const float* __restrict__ b2p,    // [1]
    const float* __restrict__ boutp,  // [1]
    float* __restrict__ out)          // [16]
{
    const int b     = blockIdx.x >> 6;
    const int itile = blockIdx.x & 63;
    const int i0    = itile * 8;
    const int tid   = threadIdx.x;

    __shared__ float pa[8][HID];
    __shared__ float w2s[HID];
    __shared__ float redw[4][8];

    pa[tid >> 5][tid & 31] = g_preA[((size_t)b * TLEN + i0 + (tid >> 5)) * HID + (tid & 31)];
    if (tid < HID) w2s[tid] = W2[tid];
    __syncthreads();

    const float* ctb = g_Ct + (size_t)b * HID * TLEN;
    const int j0 = tid, j1 = tid + 256;

    float acc[8];
    #pragma unroll
    for (int ii = 0; ii < 8; ++ii) acc[ii] = 0.f;

    for (int h = 0; h < HID; ++h) {
        const float c0v = ctb[(size_t)h * TLEN + j0];
        const float c1v = ctb[(size_t)h * TLEN + j1];
        const float w   = w2s[h];
        #pragma unroll
        for (int ii = 0; ii < 8; ++ii) {
            const float p = pa[ii][h];
            acc[ii] = fmaf(fmaxf(p + c0v, 0.f), w, acc[ii]);
            acc[ii] = fmaf(fmaxf(p + c1v, 0.f), w, acc[ii]);
        }
    }

    #pragma unroll
    for (int ii = 0; ii < 8; ++ii) {
        float v = acc[ii];
        #pragma unroll
        for (int off = 32; off >= 1; off >>= 1) v += __shfl_down(v, off);
        if ((tid & 63) == 0) redw[tid >> 6][ii] = v;
    }
    __syncthreads();

    if (tid < 8) {
        const float S = redw[0][tid] + redw[1][tid] + redw[2][tid] + redw[3][tid];
        const int i = i0 + tid;
        float diag = 0.f;
        #pragma unroll
        for (int h = 0; h < HID; ++h)
            diag = fmaf(fmaxf(pa[tid][h] + ctb[(size_t)h * TLEN + i], 0.f), w2s[h], diag);
        const float b2 = b2p[0];
        const float s = (S - diag + (float)(TLEN - 1) * b2) * 0.01f + g_un[(size_t)b * TLEN + i];
        float contrib = sigm_(s) * g_w2d[(size_t)b * TLEN + i];
        // reduce 8 lanes (lanes 0..7 of wave 0)
        contrib += __shfl_down(contrib, 4);
        contrib += __shfl_down(contrib, 2);
        contrib += __shfl_down(contrib, 1);
        if (tid == 0) {
            atomicAdd(&g_accum[b], contrib);          // one device-scope atomic
            __threadfence();
            int old = atomicAdd(&g_cnt[b], 1);
            if (old == 63) {                          // last arriver for this b
                __threadfence();
                float tot = atomicExch(&g_accum[b], 0.0f);  // read + reset
                out[b] = tot * (1.0f / (float)TLEN) + boutp[0];
                atomicExch(&g_cnt[b], 0);             // restore for next call
            }
        }
    }
}

extern "C" void kernel_launch(void* const* d_in, const int* in_sizes, int n_in,
                              void* d_out, int out_size, void* d_ws, size_t ws_size,
                              hipStream_t stream) {
    const float* sent  = (const float*)d_in[0];
    const float* h0    = (const float*)d_in[1];
    const float* c0    = (const float*)d_in[2];
    const float* Wih_f = (const float*)d_in[3];
    const float* Whh_f = (const float*)d_in[4];
    const float* b_f   = (const float*)d_in[5];
    const float* Wih_b = (const float*)d_in[6];
    const float* Whh_b = (const float*)d_in[7];
    const float* b_b   = (const float*)d_in[8];
    const float* W1    = (const float*)d_in[9];
    const float* b1    = (const float*)d_in[10];
    const float* W2    = (const float*)d_in[11];
    const float* b2    = (const float*)d_in[12];
    const float* Wu    = (const float*)d_in[13];
    const float* bu    = (const float*)d_in[14];
    const float* Wout  = (const float*)d_in[15];
    const float* bout  = (const float*)d_in[16];

    k1_lstm<<<8, 64, 0, stream>>>(sent, h0, c0, Wih_f, Whh_f, b_f,
                                  Wih_b, Whh_b, b_b);
    k2_proj<<<32, 256, 0, stream>>>(W1, b1, Wu, bu, Wout);
    k34_binary<<<1024, 256, 0, stream>>>(W2, b2, bout, (float*)d_out);
}